// Round 2
// baseline (23562.767 us; speedup 1.0000x reference)
//
#include <hip/hip_runtime.h>

// L=2, B=64, T=256, I=H=1024, G=2048
// P chunk layout: [TS][B][G] (local row m = tL*64 + b)
// h layout: [H][B] (transposed; lane = b coalesced), double-buffered hA/hB

__device__ __forceinline__ float wave_sum(float v) {
#pragma unroll
  for (int m = 1; m < 64; m <<= 1) v += __shfl_xor(v, m, 64);
  return v;
}

// ---- h init: hT[h][b] = hx[b][h]
__global__ __launch_bounds__(256) void hinit(
    const float* __restrict__ hx0, float* __restrict__ hT)
{
  int gi = (blockIdx.x << 8) + threadIdx.x;   // grid 256 -> 65536
  hT[gi] = hx0[((gi & 63) << 10) + (gi >> 6)];
}

// ---- input projection (bias dropped: BN cancels it): P[mL][n] = sum_k in[b][t0+tL][k]*w[n][k]
__global__ __launch_bounds__(256) void proj_gemm(
    const float* __restrict__ in, const float* __restrict__ w,
    float* __restrict__ P, int t0)
{
  __shared__ float As[8][132];
  __shared__ float Bs[8][132];
  const int tid = threadIdx.x;
  const int m0 = blockIdx.y << 7;      // local rows
  const int n0 = blockIdx.x << 7;
  const int tm = tid >> 4, tn = tid & 15;
  const int lr = tid >> 1;
  const int lk = (tid & 1) << 2;
  const int mA = m0 + lr;
  const int bb = mA & 63;
  const int tg = t0 + (mA >> 6);
  const float* arow = in + ((size_t)bb << 18) + ((size_t)tg << 10) + lk;
  const float* brow = w + ((size_t)(n0 + lr) << 10) + lk;
  float acc[2][2][4][4] = {};
  for (int k0 = 0; k0 < 1024; k0 += 8) {
    float4 av = *(const float4*)(arow + k0);
    float4 bv = *(const float4*)(brow + k0);
    __syncthreads();
    As[lk + 0][lr] = av.x; As[lk + 1][lr] = av.y; As[lk + 2][lr] = av.z; As[lk + 3][lr] = av.w;
    Bs[lk + 0][lr] = bv.x; Bs[lk + 1][lr] = bv.y; Bs[lk + 2][lr] = bv.z; Bs[lk + 3][lr] = bv.w;
    __syncthreads();
#pragma unroll
    for (int kk = 0; kk < 8; ++kk) {
      float4 a0 = *(const float4*)&As[kk][tm << 2];
      float4 a1 = *(const float4*)&As[kk][(tm << 2) + 64];
      float4 b0 = *(const float4*)&Bs[kk][tn << 2];
      float4 b1 = *(const float4*)&Bs[kk][(tn << 2) + 64];
      const float* ap0 = (const float*)&a0;
      const float* ap1 = (const float*)&a1;
      const float* bp0 = (const float*)&b0;
      const float* bp1 = (const float*)&b1;
#pragma unroll
      for (int i = 0; i < 4; ++i)
#pragma unroll
        for (int j = 0; j < 4; ++j) {
          acc[0][0][i][j] = fmaf(ap0[i], bp0[j], acc[0][0][i][j]);
          acc[0][1][i][j] = fmaf(ap0[i], bp1[j], acc[0][1][i][j]);
          acc[1][0][i][j] = fmaf(ap1[i], bp0[j], acc[1][0][i][j]);
          acc[1][1][i][j] = fmaf(ap1[i], bp1[j], acc[1][1][i][j]);
        }
    }
  }
#pragma unroll
  for (int mi = 0; mi < 2; ++mi)
#pragma unroll
    for (int i = 0; i < 4; ++i) {
      int m = m0 + (mi << 6) + (tm << 2) + i;
      float* prow = P + ((size_t)m << 11) + n0 + (tn << 2);
      *(float4*)prow        = make_float4(acc[mi][0][i][0], acc[mi][0][i][1], acc[mi][0][i][2], acc[mi][0][i][3]);
      *(float4*)(prow + 64) = make_float4(acc[mi][1][i][0], acc[mi][1][i][1], acc[mi][1][i][2], acc[mi][1][i][3]);
    }
}

// ---- per-(tL,g) BN stats of P -> scale/shift (in_part = P*sc + sh)
__global__ __launch_bounds__(256) void bn_stats(
    const float* __restrict__ P, const float* __restrict__ iw, const float* __restrict__ ib,
    float* __restrict__ sc, float* __restrict__ sh)
{
  const int t = blockIdx.y;                  // local
  const int g = (blockIdx.x << 8) + threadIdx.x;
  const float* col = P + (((size_t)t << 6) << 11) + g;
  float s = 0.f, q = 0.f;
#pragma unroll 8
  for (int b = 0; b < 64; ++b) { float v = col[(size_t)b << 11]; s += v; q = fmaf(v, v, q); }
  float m = s * 0.015625f;
  float var = fmaf(-m, m, q * 0.015625f);
  float scale = iw[g] * rsqrtf(var + 1e-5f);
  sc[(t << 11) + g] = scale;
  sh[(t << 11) + g] = fmaf(-m, scale, ib[g]);
}

// ---- one recurrence step, fully fused, block-local (no cross-block coupling).
// 256 blocks; block owns u-cols [bid*4, bid*4+4) and o-cols +1024.
// thread (b = tid&63, cs = tid>>6) computes full 1024-k dots for u-col g, o-col g+1024.
__global__ __launch_bounds__(256) void step_fused(
    const float* __restrict__ P, const float* __restrict__ sc, const float* __restrict__ sh,
    const float* __restrict__ whh, const float* __restrict__ hww, const float* __restrict__ hwb,
    const float* __restrict__ hin, float* __restrict__ hout,
    float* __restrict__ out, int t, int tL)
{
  const int tid = threadIdx.x, bid = blockIdx.x;
  const int b = tid & 63, cs = tid >> 6;
  const int g = (bid << 2) + cs;             // u-col; o-col = g+1024
  __shared__ float lout[64 * 5];

  const float* wu = whh + ((size_t)g << 10);
  const float* wo = whh + (((size_t)g + 1024) << 10);
  float du = 0.f, dv = 0.f;
  for (int k0 = 0; k0 < 1024; k0 += 4) {
    float h0 = hin[((k0 + 0) << 6) + b];
    float h1 = hin[((k0 + 1) << 6) + b];
    float h2 = hin[((k0 + 2) << 6) + b];
    float h3 = hin[((k0 + 3) << 6) + b];
    float4 a = *(const float4*)(wu + k0);
    float4 c = *(const float4*)(wo + k0);
    du = fmaf(h0, a.x, du); du = fmaf(h1, a.y, du);
    du = fmaf(h2, a.z, du); du = fmaf(h3, a.w, du);
    dv = fmaf(h0, c.x, dv); dv = fmaf(h1, c.y, dv);
    dv = fmaf(h2, c.z, dv); dv = fmaf(h3, c.w, dv);
  }
  // BN over batch (wave lanes = the 64 batches)
  float su = wave_sum(du), qu = wave_sum(du * du);
  float so = wave_sum(dv), qo = wave_sum(dv * dv);
  float mu = su * 0.015625f, vu = fmaf(-mu, mu, qu * 0.015625f);
  float mo = so * 0.015625f, vo = fmaf(-mo, mo, qo * 0.015625f);
  float hpu = (du - mu) * (hww[g] * rsqrtf(vu + 1e-5f)) + hwb[g];
  float hpo = (dv - mo) * (hww[g + 1024] * rsqrtf(vo + 1e-5f)) + hwb[g + 1024];
  const size_t prow = ((size_t)((tL << 6) + b)) << 11;
  float inu = fmaf(P[prow + g],        sc[(tL << 11) + g],        sh[(tL << 11) + g]);
  float ino = fmaf(P[prow + g + 1024], sc[(tL << 11) + g + 1024], sh[(tL << 11) + g + 1024]);
  float ug = 1.f / (1.f + expf(-(inu + hpu)));
  float og = fmaxf(ino + hpo, 0.f);
  float hold = hin[(g << 6) + b];
  float hnew = fmaf(ug, hold - og, og);      // ug*h + (1-ug)*og
  hout[(g << 6) + b] = hnew;
  lout[b * 5 + cs] = hnew;
  __syncthreads();
  {
    int b2 = tid >> 2, j2 = tid & 3;
    out[(((size_t)(b2 << 8) + t) << 10) + (bid << 2) + j2] = lout[b2 * 5 + j2];
  }
}

extern "C" void kernel_launch(void* const* d_in, const int* in_sizes, int n_in,
                              void* d_out, int out_size, void* d_ws, size_t ws_size,
                              hipStream_t stream) {
  const float* x   = (const float*)d_in[0];
  const float* hx  = (const float*)d_in[1];
  const float* wih = (const float*)d_in[2];
  const float* whh = (const float*)d_in[3];
  // d_in[4], d_in[5] = b_ih, b_hh: cancelled exactly by batch-norm mean subtraction
  const float* biw = (const float*)d_in[6];
  const float* bib = (const float*)d_in[7];
  const float* bhw = (const float*)d_in[8];
  const float* bhb = (const float*)d_in[9];
  float* out = (float*)d_out;

  // ws_size-adaptive T-chunking: floats needed = TS*131072 (P) + TS*4096 (sc,sh) + 131072 (hA,hB)
  const size_t wsf = ws_size / 4;
  int TS = 256;
  while (TS > 2) {
    size_t need = (size_t)TS * 131072 + (size_t)TS * 4096 + 131072;
    if (need <= wsf) break;
    TS >>= 1;
  }
  float* P  = (float*)d_ws;
  float* sc = P + (size_t)TS * 131072;
  float* sh = sc + (size_t)TS * 2048;
  float* hA = sh + (size_t)TS * 2048;
  float* hB = hA + 65536;

  for (int layer = 0; layer < 2; ++layer) {
    const float* inp   = layer ? (const float*)out : x;
    const float* wih_l = wih + (size_t)layer * 2048 * 1024;
    const float* whh_l = whh + (size_t)layer * 2048 * 1024;
    const float* biw_l = biw + layer * 2048;
    const float* bib_l = bib + layer * 2048;
    const float* bhw_l = bhw + layer * 2048;
    const float* bhb_l = bhb + layer * 2048;
    const float* hx_l  = hx + (size_t)layer * 65536;

    hinit<<<dim3(256), 256, 0, stream>>>(hx_l, hA);
    for (int t0 = 0; t0 < 256; t0 += TS) {
      proj_gemm<<<dim3(16, TS / 2), 256, 0, stream>>>(inp, wih_l, P, t0);
      bn_stats<<<dim3(8, TS), 256, 0, stream>>>(P, biw_l, bib_l, sc, sh);
      for (int t = t0; t < t0 + TS; ++t) {
        const float* hin = (t & 1) ? hB : hA;
        float*      hout = (t & 1) ? hA : hB;
        step_fused<<<dim3(256), 256, 0, stream>>>(P, sc, sh, whh_l, bhw_l, bhb_l,
                                                  hin, hout, out, t, t - t0);
      }
    }
  }
}